// Round 6
// baseline (460.113 us; speedup 1.0000x reference)
//
#include <hip/hip_runtime.h>

typedef __bf16 bf16;
typedef __bf16 bf16x8 __attribute__((ext_vector_type(8)));
typedef __bf16 bf16x4 __attribute__((ext_vector_type(4)));
typedef float f32x4 __attribute__((ext_vector_type(4)));
typedef unsigned int u32;
typedef unsigned short u16;

#define MFMA_BF16 __builtin_amdgcn_mfma_f32_16x16x32_bf16

#define GLOAD_LDS(g, l)                                        \
  __builtin_amdgcn_global_load_lds(                            \
      (__attribute__((address_space(1))) void*)(g),            \
      (__attribute__((address_space(3))) void*)(l), 16, 0, 0)

// ---------------------------------------------------------------- utilities
__global__ void cvt_f32_bf16(const float* __restrict__ in, bf16* __restrict__ out, int n) {
  int i = (blockIdx.x * blockDim.x + threadIdx.x) * 4;
  if (i >= n) return;
  float4 v = *(const float4*)(in + i);
  bf16x4 o;
  o[0] = (bf16)v.x; o[1] = (bf16)v.y; o[2] = (bf16)v.z; o[3] = (bf16)v.w;
  *(bf16x4*)(out + i) = o;
}

// W [K][N] fp32 -> Wt [N][K] bf16
__global__ void transpose_w(const float* __restrict__ w, bf16* __restrict__ wt, int K, int N) {
  __shared__ float tile[32][33];
  int n0 = blockIdx.x * 32, k0 = blockIdx.y * 32;
  int t = threadIdx.x;
  int c = t & 31, r = t >> 5;
#pragma unroll
  for (int i = 0; i < 4; i++)
    tile[r + i * 8][c] = w[(size_t)(k0 + r + i * 8) * N + n0 + c];
  __syncthreads();
#pragma unroll
  for (int i = 0; i < 4; i++)
    wt[(size_t)(n0 + r + i * 8) * K + k0 + c] = (bf16)tile[c][r + i * 8];
}

__device__ inline float gelu_exact(float x) {
  return 0.5f * x * (1.0f + erff(x * 0.70710678118654752f));
}

// ---------------------------------------------------------------- GEMM
// C[M][N] = A[M][K] * Bt[N][K]^T, 128x128 tile, BK=32, 4 waves.
// Ring-4 LDS staging (64 KB, 2 blocks/CU): prefetch distance 3 K-steps
// (~700 cyc in flight) with counted vmcnt(8) steady-state — never 0 until
// the tail. lgkmcnt(0) before the barrier keeps ds_reads of buffer t-1
// drained before stage(t+3) overwrites it. LDS reads 2-way-free via XOR
// swizzle (read side + pre-swizzled global source, linear LDS dest).
// 1-D grid, XCD-chunked M-fastest order.
template <int MODE>
__global__ __launch_bounds__(256, 2) void gemm_bt(
    const bf16* __restrict__ A, const bf16* __restrict__ Bt,
    bf16* __restrict__ outb, float* __restrict__ outf,
    const float* __restrict__ resid, int K, int N) {
  __shared__ __align__(16) bf16 As[4][128 * 32];
  __shared__ __align__(16) bf16 Bs[4][128 * 32];
  const int tid = threadIdx.x;
  const int lane = tid & 63, w = tid >> 6;
  const int g = lane >> 4, l15 = lane & 15;

  // XCD-chunked mapping (nwg always multiple of 8; M-tiles = 64)
  const int cpx = gridDim.x >> 3;
  const int widx = (blockIdx.x & 7) * cpx + (blockIdx.x >> 3);
  const int m0 = (widx & 63) * 128, n0 = (widx >> 6) * 128;
  const int wm = w >> 1, wn = w & 1;

  f32x4 acc[4][4] = {};

  // staging: wave w covers rows i*64 + w*16 + lane/4; 16B chunk pre-swizzled
  const int srow = w * 16 + (lane >> 2);
  const int schunk = (lane & 3) ^ ((lane >> 3) & 3);
  const int scolb = schunk * 16;
  const char* gA = (const char*)A;
  const char* gB = (const char*)Bt;
  const size_t gA0 = ((size_t)(m0 + srow) * K) * 2 + scolb;
  const size_t gA1 = ((size_t)(m0 + 64 + srow) * K) * 2 + scolb;
  const size_t gB0 = ((size_t)(n0 + srow) * K) * 2 + scolb;
  const size_t gB1 = ((size_t)(n0 + 64 + srow) * K) * 2 + scolb;

  auto stage = [&](int kt, int c) {
    const size_t kb = (size_t)kt * 64;  // kt*32 elems * 2B
    GLOAD_LDS(gA + gA0 + kb, &As[c][w * 512]);
    GLOAD_LDS(gA + gA1 + kb, &As[c][2048 + w * 512]);
    GLOAD_LDS(gB + gB0 + kb, &Bs[c][w * 512]);
    GLOAD_LDS(gB + gB1 + kb, &Bs[c][2048 + w * 512]);
  };

  // read offsets (bytes): row*64 + swizzled 16B chunk
  const int rsw = (g ^ ((l15 >> 1) & 3)) << 4;
  const int rdA = (wm * 64 + l15) * 64 + rsw;
  const int rdB = (wn * 64 + l15) * 64 + rsw;

  const int T = K >> 5;
  stage(0, 0);
  stage(1, 1);
  stage(2, 2);

  int cur = 0;
  for (int t = 0; t < T; ++t) {
    // wait for stage(t): outstanding = stages t..t+2 (12 loads) steady-state
    if (t < T - 2)       asm volatile("s_waitcnt vmcnt(8)" ::: "memory");
    else if (t == T - 2) asm volatile("s_waitcnt vmcnt(4)" ::: "memory");
    else                 asm volatile("s_waitcnt vmcnt(0)" ::: "memory");
    asm volatile("s_waitcnt lgkmcnt(0)" ::: "memory");
    __builtin_amdgcn_s_barrier();
    __builtin_amdgcn_sched_barrier(0);
    if (t + 3 < T) stage(t + 3, (cur + 3) & 3);
    const char* pA = (const char*)As[cur];
    const char* pB = (const char*)Bs[cur];
    bf16x8 af[4], bfr[4];
#pragma unroll
    for (int mi = 0; mi < 4; mi++) af[mi] = *(const bf16x8*)(pA + rdA + mi * 1024);
#pragma unroll
    for (int ni = 0; ni < 4; ni++) bfr[ni] = *(const bf16x8*)(pB + rdB + ni * 1024);
#pragma unroll
    for (int mi = 0; mi < 4; mi++)
#pragma unroll
      for (int ni = 0; ni < 4; ni++)
        acc[mi][ni] = MFMA_BF16(af[mi], bfr[ni], acc[mi][ni], 0, 0, 0);
    cur = (cur + 1) & 3;
  }

  const int row_base = m0 + wm * 64;
  const int col_base = n0 + wn * 64 + l15;
#pragma unroll
  for (int mi = 0; mi < 4; mi++)
#pragma unroll
    for (int ni = 0; ni < 4; ni++) {
      const int c = col_base + ni * 16;
#pragma unroll
      for (int r = 0; r < 4; r++) {
        const int row = row_base + mi * 16 + 4 * g + r;
        const size_t idx = (size_t)row * N + c;
        float v = acc[mi][ni][r];
        if constexpr (MODE == 0) {
          outb[idx] = (bf16)v;
        } else if constexpr (MODE == 1) {
          float xv = v + resid[idx];
          outf[idx] = xv;
          outb[idx] = (bf16)xv;
        } else if constexpr (MODE == 2) {
          outb[idx] = (bf16)gelu_exact(v);
        } else {
          outf[idx] = v + resid[idx];
        }
      }
    }
}

// ---------------------------------------------------------------- attention
// (unchanged: 512 thr, BQ=128, paired q-tiles, K+V^T in LDS dbuf,
//  single barrier/step, register prefetch, permuted-K QK^T)
__global__ __launch_bounds__(512, 2) void attn_fwd(const bf16* __restrict__ qkv,
                                                   bf16* __restrict__ O) {
  __shared__ __align__(16) char Kl[2][64 * 128];
  __shared__ __align__(16) char Vt[2][64 * 128];
  const int tid = threadIdx.x;
  const int lane = tid & 63, w = tid >> 6;
  const int g = lane >> 4, l15 = lane & 15;
  const int bh = blockIdx.x;
  const int bx = blockIdx.y;
  const int b = bh >> 4, hh = bh & 15;
  const size_t tokbase = (size_t)b * 2048;

  const bf16* kbase = qkv + tokbase * 3072 + 1024 + hh * 64;
  const bf16* vbase = qkv + tokbase * 3072 + 2048 + hh * 64;
  const int kperm = 8 * (l15 >> 2) + (l15 & 3);

  const bool vstage = tid < 256;
  const int t2 = tid & 255;
  const int vrg = t2 >> 4, vds = (t2 & 15) * 4;
  const int krow = t2 >> 2, ksl = t2 & 3;
  const int kswzr = (krow & 3) | ((krow & 8) >> 1);

  union U4 { ushort4 v; u16 a[4]; };
  U4 vr[4];
  uint4 kpr0, kpr1;

  auto prefetch = [&](int k0n) {
    if (vstage) {
#pragma unroll
      for (int i4 = 0; i4 < 4; i4++)
        vr[i4].v = *(const ushort4*)(vbase + (size_t)(k0n + 4 * vrg + i4) * 3072 + vds);
    } else {
      const bf16* kp = kbase + (size_t)(k0n + krow) * 3072 + 8 * ksl;
      kpr0 = *(const uint4*)(kp);
      kpr1 = *(const uint4*)(kp + 32);
    }
  };

  prefetch(0);
  int cur = 0;

  for (int half = 0; half < 2; half++) {
    const int xT = half ? (15 - bx) : bx;
    const int q0 = xT * 128;
    const int qw0 = q0 + 16 * w;
    const int qi = qw0 + l15;
    const int kend = q0 + 128;

    const bf16* qptr = qkv + (tokbase + qw0 + l15) * 3072 + hh * 64 + 8 * g;
    const bf16x8 qf0 = *(const bf16x8*)(qptr);
    const bf16x8 qf1 = *(const bf16x8*)(qptr + 32);

    f32x4 ot[4] = {};
    float m_i = -INFINITY, l_i = 0.0f;

    for (int k0 = 0; k0 < kend; k0 += 64) {
      char* Kc = Kl[cur];
      char* Vc = Vt[cur];
      if (vstage) {
#pragma unroll
        for (int dj = 0; dj < 4; dj++) {
          const int d = vds + dj;
          u32 lo = (u32)vr[0].a[dj] | ((u32)vr[1].a[dj] << 16);
          u32 hi = (u32)vr[2].a[dj] | ((u32)vr[3].a[dj] << 16);
          const int boff = d * 128 + ((((vrg >> 1) ^ ((d >> 1) & 7)) << 4)) + ((vrg & 1) << 3);
          *(uint2*)(Vc + boff) = make_uint2(lo, hi);
        }
      } else {
        *(uint4*)(Kc + krow * 128 + ((ksl ^ kswzr) << 4)) = kpr0;
        *(uint4*)(Kc + krow * 128 + (((ksl | 4) ^ kswzr) << 4)) = kpr1;
      }
      __syncthreads();

      const int k0n = (k0 + 64 < kend) ? k0 + 64 : 0;
      prefetch(k0n);

      if (k0 <= qw0 + 15) {
        const bool lastT = (k0 + 63 > qw0);
        const int npair = lastT ? (((qw0 + 15 - k0) >> 5) + 1) : 2;

        f32x4 st[4];
#pragma unroll
        for (int ip = 0; ip < 2; ip++)
          if (ip < npair) {
#pragma unroll
            for (int h2 = 0; h2 < 2; h2++) {
              const int kr = 32 * ip + 4 * h2 + kperm;
              const int swzk = (kr & 3) | ((kr & 8) >> 1);
              const char* kro = Kc + kr * 128;
              bf16x8 ka = *(const bf16x8*)(kro + ((g ^ swzk) << 4));
              bf16x8 kb = *(const bf16x8*)(kro + (((g | 4) ^ swzk) << 4));
              f32x4 z = {};
              z = MFMA_BF16(ka, qf0, z, 0, 0, 0);
              st[2 * ip + h2] = MFMA_BF16(kb, qf1, z, 0, 0, 0);
            }
          }

        float p[4][4];
        float mt = -INFINITY;
#pragma unroll
        for (int ip = 0; ip < 2; ip++)
          if (ip < npair) {
#pragma unroll
            for (int h2 = 0; h2 < 2; h2++)
#pragma unroll
              for (int r = 0; r < 4; r++) {
                const int kk = k0 + 32 * ip + 8 * g + 4 * h2 + r;
                float v = (float)st[2 * ip + h2][r] * 0.125f;
                if (lastT && kk > qi) v = -INFINITY;
                p[2 * ip + h2][r] = v;
                mt = fmaxf(mt, v);
              }
          }
        mt = fmaxf(mt, __shfl_xor(mt, 16, 64));
        mt = fmaxf(mt, __shfl_xor(mt, 32, 64));

        if (!__all(mt - m_i <= 8.0f)) {
          const float m_new = fmaxf(m_i, mt);
          const float alpha = __expf(m_i - m_new);
          l_i *= alpha;
#pragma unroll
          for (int dt = 0; dt < 4; dt++)
#pragma unroll
            for (int r = 0; r < 4; r++) ot[dt][r] *= alpha;
          m_i = m_new;
        }
        float s = 0.0f;
#pragma unroll
        for (int ip = 0; ip < 2; ip++)
          if (ip < npair) {
#pragma unroll
            for (int h2 = 0; h2 < 2; h2++)
#pragma unroll
              for (int r = 0; r < 4; r++) {
                float e = __expf(p[2 * ip + h2][r] - m_i);
                p[2 * ip + h2][r] = e;
                s += e;
              }
          }
        s += __shfl_xor(s, 16, 64);
        s += __shfl_xor(s, 32, 64);
        l_i += s;

#pragma unroll
        for (int ip = 0; ip < 2; ip++)
          if (ip < npair) {
            bf16x8 pf;
#pragma unroll
            for (int h2 = 0; h2 < 2; h2++)
#pragma unroll
              for (int r = 0; r < 4; r++) pf[4 * h2 + r] = (bf16)p[2 * ip + h2][r];
#pragma unroll
            for (int dt = 0; dt < 4; dt++) {
              const bf16x8 vf = *(const bf16x8*)(
                  Vc + (dt * 16 + l15) * 128 + (((4 * ip + g) ^ (l15 >> 1)) << 4));
              ot[dt] = MFMA_BF16(vf, pf, ot[dt], 0, 0, 0);
            }
          }
      }
      cur ^= 1;
    }

    const float inv = 1.0f / l_i;
    bf16* obase = O + (tokbase + qw0 + l15) * 1024 + hh * 64;
#pragma unroll
    for (int dt = 0; dt < 4; dt++) {
      bf16x4 ov;
#pragma unroll
      for (int r = 0; r < 4; r++) ov[r] = (bf16)(ot[dt][r] * inv);
      *(bf16x4*)(obase + dt * 16 + 4 * g) = ov;
    }
  }
}

// ---------------------------------------------------------------- launch
extern "C" void kernel_launch(void* const* d_in, const int* in_sizes, int n_in,
                              void* d_out, int out_size, void* d_ws, size_t ws_size,
                              hipStream_t stream) {
  const float* x = (const float*)d_in[0];
  const float* w_qkv = (const float*)d_in[1];
  const float* w_out = (const float*)d_in[2];
  const float* w_ff1 = (const float*)d_in[3];
  const float* w_ff2 = (const float*)d_in[4];
  float* out = (float*)d_out;

  char* ws = (char*)d_ws;
  size_t off = 0;
  auto alloc = [&](size_t bytes) {
    void* p = ws + off;
    off += (bytes + 255) & ~(size_t)255;
    return p;
  };
  const size_t M = 8192;
  bf16* X16   = (bf16*)alloc(M * 1024 * 2);
  bf16* WqkvT = (bf16*)alloc(3072ull * 1024 * 2);
  bf16* WoutT = (bf16*)alloc(1024ull * 1024 * 2);
  bf16* Wff1T = (bf16*)alloc(4096ull * 1024 * 2);
  bf16* Wff2T = (bf16*)alloc(1024ull * 4096 * 2);
  bf16* QKV   = (bf16*)alloc(M * 3072 * 2);
  bf16* Obuf  = (bf16*)alloc(M * 1024 * 2);
  float* x1   = (float*)alloc(M * 1024 * 4);
  bf16* x1b   = (bf16*)alloc(M * 1024 * 2);
  bf16* Hbuf  = (bf16*)alloc(M * 4096 * 2);

  cvt_f32_bf16<<<8192, 256, 0, stream>>>(x, X16, 8192 * 1024);
  transpose_w<<<dim3(3072 / 32, 1024 / 32), 256, 0, stream>>>(w_qkv, WqkvT, 1024, 3072);
  transpose_w<<<dim3(1024 / 32, 1024 / 32), 256, 0, stream>>>(w_out, WoutT, 1024, 1024);
  transpose_w<<<dim3(4096 / 32, 1024 / 32), 256, 0, stream>>>(w_ff1, Wff1T, 1024, 4096);
  transpose_w<<<dim3(1024 / 32, 4096 / 32), 256, 0, stream>>>(w_ff2, Wff2T, 4096, 1024);

  // 1-D grids: nwg = (N/128)*(M/128), M-tiles=64 fastest inside XCD chunks
  gemm_bt<0><<<24 * 64, 256, 0, stream>>>(X16, WqkvT, QKV, nullptr, nullptr, 1024, 3072);
  attn_fwd<<<dim3(64, 8), 512, 0, stream>>>(QKV, Obuf);
  gemm_bt<1><<<8 * 64, 256, 0, stream>>>(Obuf, WoutT, x1b, x1, x, 1024, 1024);
  gemm_bt<2><<<32 * 64, 256, 0, stream>>>(x1b, Wff1T, Hbuf, nullptr, nullptr, 1024, 4096);
  gemm_bt<3><<<8 * 64, 256, 0, stream>>>(Hbuf, Wff2T, nullptr, out, x1, 4096, 1024);
}

// Round 7
// 398.601 us; speedup vs baseline: 1.1543x; 1.1543x over previous
//
#include <hip/hip_runtime.h>

typedef __bf16 bf16;
typedef __bf16 bf16x8 __attribute__((ext_vector_type(8)));
typedef __bf16 bf16x4 __attribute__((ext_vector_type(4)));
typedef float f32x4 __attribute__((ext_vector_type(4)));
typedef unsigned int u32;
typedef unsigned short u16;

#define MFMA_BF16 __builtin_amdgcn_mfma_f32_16x16x32_bf16

#define GLOAD_LDS(g, l)                                        \
  __builtin_amdgcn_global_load_lds(                            \
      (__attribute__((address_space(1))) void*)(g),            \
      (__attribute__((address_space(3))) void*)(l), 16, 0, 0)

// ---------------------------------------------------------------- utilities
__global__ void cvt_f32_bf16(const float* __restrict__ in, bf16* __restrict__ out, int n) {
  int i = (blockIdx.x * blockDim.x + threadIdx.x) * 4;
  if (i >= n) return;
  float4 v = *(const float4*)(in + i);
  bf16x4 o;
  o[0] = (bf16)v.x; o[1] = (bf16)v.y; o[2] = (bf16)v.z; o[3] = (bf16)v.w;
  *(bf16x4*)(out + i) = o;
}

// W [K][N] fp32 -> Wt [N][K] bf16
__global__ void transpose_w(const float* __restrict__ w, bf16* __restrict__ wt, int K, int N) {
  __shared__ float tile[32][33];
  int n0 = blockIdx.x * 32, k0 = blockIdx.y * 32;
  int t = threadIdx.x;
  int c = t & 31, r = t >> 5;
#pragma unroll
  for (int i = 0; i < 4; i++)
    tile[r + i * 8][c] = w[(size_t)(k0 + r + i * 8) * N + n0 + c];
  __syncthreads();
#pragma unroll
  for (int i = 0; i < 4; i++)
    wt[(size_t)(n0 + r + i * 8) * K + k0 + c] = (bf16)tile[c][r + i * 8];
}

__device__ inline float gelu_exact(float x) {
  return 0.5f * x * (1.0f + erff(x * 0.70710678118654752f));
}

// ---------------------------------------------------------------- GEMM
// 256x(NF*64) tile, BK=64, 512 threads = 8 waves (2M x 4N). Wave tile:
// 128 x (NF*16); acc[8][NF]. 8-phase-per-2-Ktile schedule collapsed to
// 4 phases/K-tile (one C-quadrant each): barrier -> [stage] -> ds_read ->
// lgkmcnt(0) -> setprio(1) -> MFMA cluster -> setprio(0).
// Staging runs TWO K-tiles ahead into slot kt&1 with counted vmcnt(4+NF),
// never 0 in the main loop. Safety: each staged region's last LDS read is
// >=1 phase before its stage-issue (A: read ph0/ph2, staged ph3; B: read
// ph0/ph1, staged ph2); per-phase barriers order read-completion (lgkmcnt
// before MFMA) ahead of stage-issue; global-load return latency >> same-
// window ds_read service. LDS reads swizzled chunk^=(row&7), inverse
// applied on per-lane GLOBAL source, LDS dest linear (gload_lds rule).
template <int MODE, int NF>
__global__ __launch_bounds__(512, 2) void gemm_bt(
    const bf16* __restrict__ A, const bf16* __restrict__ Bt,
    bf16* __restrict__ outb, float* __restrict__ outf,
    const float* __restrict__ resid, int K, int N) {
  __shared__ __align__(16) bf16 As[2][256 * 64];
  __shared__ __align__(16) bf16 Bs[2][NF * 64 * 64];
  const int tid = threadIdx.x;
  const int lane = tid & 63, w = tid >> 6;
  const int g = lane >> 4, l15 = lane & 15;
  const int wm = w >> 2, wn = w & 3;

  // XCD-chunked mapping; M-tiles (32) fastest within each XCD chunk
  const int cpx = (int)gridDim.x >> 3;
  const int widx = ((int)blockIdx.x & 7) * cpx + ((int)blockIdx.x >> 3);
  const int m0 = (widx & 31) * 256, n0 = (widx >> 5) * (NF * 64);

  f32x4 acc[8][NF] = {};

  // ---- staging maps: issue i covers 64 rows; wave w rows w*8+(lane>>3)
  const int srow8 = w * 8 + (lane >> 3);
  const int schunk = (lane & 7) ^ ((lane >> 3) & 7);  // inverse read-swizzle
  const char* gA = (const char*)A;
  const char* gB = (const char*)Bt;
  const size_t aBase = ((size_t)(m0 + srow8) * K + schunk * 8) * 2;
  const size_t bBase = ((size_t)(n0 + srow8) * K + schunk * 8) * 2;

  auto stageA = [&](int kt, int slot, int i) {
    GLOAD_LDS(gA + aBase + ((size_t)(i * 64) * K + (size_t)kt * 64) * 2,
              &As[slot][(i * 64 + w * 8) * 64]);
  };
  auto stageB = [&](int kt, int slot, int i) {
    GLOAD_LDS(gB + bBase + ((size_t)(i * 64) * K + (size_t)kt * 64) * 2,
              &Bs[slot][(i * 64 + w * 8) * 64]);
  };

  // ---- fragment read offsets (bytes). row&7 == l15&7 for all frags.
  const int arow0 = (wm * 128 + l15) * 128;
  const int brow0 = (wn * 16 * NF + l15) * 128;
  const int csw0 = ((g) ^ (l15 & 7)) << 4;
  const int csw1 = ((4 + g) ^ (l15 & 7)) << 4;

  const int T = K >> 6;
  // prologue: stage tiles 0 and 1
#pragma unroll
  for (int i = 0; i < 4; i++) stageA(0, 0, i);
#pragma unroll
  for (int i = 0; i < NF; i++) stageB(0, 0, i);
#pragma unroll
  for (int i = 0; i < 4; i++) stageA(1, 1, i);
#pragma unroll
  for (int i = 0; i < NF; i++) stageB(1, 1, i);

  bf16x8 a[4][2], b0[NF / 2][2], b1[NF / 2][2];

  for (int kt = 0; kt < T; ++kt) {
    const int slot = kt & 1;
    const char* pA = (const char*)As[slot];
    const char* pB = (const char*)Bs[slot];

    // ================= phase 0: quadrant (mh0, nh0)
    if (kt < T - 1) {
      if constexpr (NF == 4) asm volatile("s_waitcnt vmcnt(8)" ::: "memory");
      else                   asm volatile("s_waitcnt vmcnt(6)" ::: "memory");
    } else {
      asm volatile("s_waitcnt vmcnt(0)" ::: "memory");
    }
    __builtin_amdgcn_s_barrier();
    __builtin_amdgcn_sched_barrier(0);
#pragma unroll
    for (int mi = 0; mi < 4; mi++) {
      a[mi][0] = *(const bf16x8*)(pA + arow0 + mi * 2048 + csw0);
      a[mi][1] = *(const bf16x8*)(pA + arow0 + mi * 2048 + csw1);
    }
#pragma unroll
    for (int ni = 0; ni < NF / 2; ni++) {
      b0[ni][0] = *(const bf16x8*)(pB + brow0 + ni * 2048 + csw0);
      b0[ni][1] = *(const bf16x8*)(pB + brow0 + ni * 2048 + csw1);
    }
    asm volatile("s_waitcnt lgkmcnt(0)" ::: "memory");
    __builtin_amdgcn_sched_barrier(0);
    __builtin_amdgcn_s_setprio(1);
#pragma unroll
    for (int kk = 0; kk < 2; kk++)
#pragma unroll
      for (int mi = 0; mi < 4; mi++)
#pragma unroll
        for (int ni = 0; ni < NF / 2; ni++)
          acc[mi][ni] = MFMA_BF16(a[mi][kk], b0[ni][kk], acc[mi][ni], 0, 0, 0);
    __builtin_amdgcn_s_setprio(0);

    // ================= phase 1: quadrant (mh0, nh1)
    __builtin_amdgcn_s_barrier();
#pragma unroll
    for (int ni = 0; ni < NF / 2; ni++) {
      b1[ni][0] = *(const bf16x8*)(pB + brow0 + NF * 1024 + ni * 2048 + csw0);
      b1[ni][1] = *(const bf16x8*)(pB + brow0 + NF * 1024 + ni * 2048 + csw1);
    }
    asm volatile("s_waitcnt lgkmcnt(0)" ::: "memory");
    __builtin_amdgcn_sched_barrier(0);
    __builtin_amdgcn_s_setprio(1);
#pragma unroll
    for (int kk = 0; kk < 2; kk++)
#pragma unroll
      for (int mi = 0; mi < 4; mi++)
#pragma unroll
        for (int ni = 0; ni < NF / 2; ni++)
          acc[mi][NF / 2 + ni] = MFMA_BF16(a[mi][kk], b1[ni][kk], acc[mi][NF / 2 + ni], 0, 0, 0);
    __builtin_amdgcn_s_setprio(0);

    // ================= phase 2: quadrant (mh1, nh1); stage B(kt+2)
    __builtin_amdgcn_s_barrier();
    if (kt + 2 < T) {
#pragma unroll
      for (int i = 0; i < NF; i++) stageB(kt + 2, slot, i);
    }
#pragma unroll
    for (int mi = 0; mi < 4; mi++) {
      a[mi][0] = *(const bf16x8*)(pA + arow0 + 8192 + mi * 2048 + csw0);
      a[mi][1] = *(const bf16x8*)(pA + arow0 + 8192 + mi * 2048 + csw1);
    }
    asm volatile("s_waitcnt lgkmcnt(0)" ::: "memory");
    __builtin_amdgcn_sched_barrier(0);
    __builtin_amdgcn_s_setprio(1);
#pragma unroll
    for (int kk = 0; kk < 2; kk++)
#pragma unroll
      for (int mi = 0; mi < 4; mi++)
#pragma unroll
        for (int ni = 0; ni < NF / 2; ni++)
          acc[4 + mi][NF / 2 + ni] = MFMA_BF16(a[mi][kk], b1[ni][kk], acc[4 + mi][NF / 2 + ni], 0, 0, 0);
    __builtin_amdgcn_s_setprio(0);

    // ================= phase 3: quadrant (mh1, nh0); stage A(kt+2)
    __builtin_amdgcn_s_barrier();
    if (kt + 2 < T) {
#pragma unroll
      for (int i = 0; i < 4; i++) stageA(kt + 2, slot, i);
    }
    __builtin_amdgcn_s_setprio(1);
#pragma unroll
    for (int kk = 0; kk < 2; kk++)
#pragma unroll
      for (int mi = 0; mi < 4; mi++)
#pragma unroll
        for (int ni = 0; ni < NF / 2; ni++)
          acc[4 + mi][ni] = MFMA_BF16(a[mi][kk], b0[ni][kk], acc[4 + mi][ni], 0, 0, 0);
    __builtin_amdgcn_s_setprio(0);
  }

  // ---- epilogue
  const int row_base = m0 + wm * 128;
  const int col_base = n0 + wn * 16 * NF + l15;
#pragma unroll
  for (int mi = 0; mi < 8; mi++)
#pragma unroll
    for (int ni = 0; ni < NF; ni++) {
      const int c = col_base + ni * 16;
#pragma unroll
      for (int r = 0; r < 4; r++) {
        const int row = row_base + mi * 16 + 4 * g + r;
        const size_t idx = (size_t)row * N + c;
        float v = acc[mi][ni][r];
        if constexpr (MODE == 0) {
          outb[idx] = (bf16)v;
        } else if constexpr (MODE == 1) {
          float xv = v + resid[idx];
          outf[idx] = xv;
          outb[idx] = (bf16)xv;
        } else if constexpr (MODE == 2) {
          outb[idx] = (bf16)gelu_exact(v);
        } else {
          outf[idx] = v + resid[idx];
        }
      }
    }
}

// ---------------------------------------------------------------- attention
// (unchanged: 512 thr, BQ=128, paired q-tiles, K+V^T in LDS dbuf,
//  single barrier/step, register prefetch, permuted-K QK^T)
__global__ __launch_bounds__(512, 2) void attn_fwd(const bf16* __restrict__ qkv,
                                                   bf16* __restrict__ O) {
  __shared__ __align__(16) char Kl[2][64 * 128];
  __shared__ __align__(16) char Vt[2][64 * 128];
  const int tid = threadIdx.x;
  const int lane = tid & 63, w = tid >> 6;
  const int g = lane >> 4, l15 = lane & 15;
  const int bh = blockIdx.x;
  const int bx = blockIdx.y;
  const int b = bh >> 4, hh = bh & 15;
  const size_t tokbase = (size_t)b * 2048;

  const bf16* kbase = qkv + tokbase * 3072 + 1024 + hh * 64;
  const bf16* vbase = qkv + tokbase * 3072 + 2048 + hh * 64;
  const int kperm = 8 * (l15 >> 2) + (l15 & 3);

  const bool vstage = tid < 256;
  const int t2 = tid & 255;
  const int vrg = t2 >> 4, vds = (t2 & 15) * 4;
  const int krow = t2 >> 2, ksl = t2 & 3;
  const int kswzr = (krow & 3) | ((krow & 8) >> 1);

  union U4 { ushort4 v; u16 a[4]; };
  U4 vr[4];
  uint4 kpr0, kpr1;

  auto prefetch = [&](int k0n) {
    if (vstage) {
#pragma unroll
      for (int i4 = 0; i4 < 4; i4++)
        vr[i4].v = *(const ushort4*)(vbase + (size_t)(k0n + 4 * vrg + i4) * 3072 + vds);
    } else {
      const bf16* kp = kbase + (size_t)(k0n + krow) * 3072 + 8 * ksl;
      kpr0 = *(const uint4*)(kp);
      kpr1 = *(const uint4*)(kp + 32);
    }
  };

  prefetch(0);
  int cur = 0;

  for (int half = 0; half < 2; half++) {
    const int xT = half ? (15 - bx) : bx;
    const int q0 = xT * 128;
    const int qw0 = q0 + 16 * w;
    const int qi = qw0 + l15;
    const int kend = q0 + 128;

    const bf16* qptr = qkv + (tokbase + qw0 + l15) * 3072 + hh * 64 + 8 * g;
    const bf16x8 qf0 = *(const bf16x8*)(qptr);
    const bf16x8 qf1 = *(const bf16x8*)(qptr + 32);

    f32x4 ot[4] = {};
    float m_i = -INFINITY, l_i = 0.0f;

    for (int k0 = 0; k0 < kend; k0 += 64) {
      char* Kc = Kl[cur];
      char* Vc = Vt[cur];
      if (vstage) {
#pragma unroll
        for (int dj = 0; dj < 4; dj++) {
          const int d = vds + dj;
          u32 lo = (u32)vr[0].a[dj] | ((u32)vr[1].a[dj] << 16);
          u32 hi = (u32)vr[2].a[dj] | ((u32)vr[3].a[dj] << 16);
          const int boff = d * 128 + ((((vrg >> 1) ^ ((d >> 1) & 7)) << 4)) + ((vrg & 1) << 3);
          *(uint2*)(Vc + boff) = make_uint2(lo, hi);
        }
      } else {
        *(uint4*)(Kc + krow * 128 + ((ksl ^ kswzr) << 4)) = kpr0;
        *(uint4*)(Kc + krow * 128 + (((ksl | 4) ^ kswzr) << 4)) = kpr1;
      }
      __syncthreads();

      const int k0n = (k0 + 64 < kend) ? k0 + 64 : 0;
      prefetch(k0n);

      if (k0 <= qw0 + 15) {
        const bool lastT = (k0 + 63 > qw0);
        const int npair = lastT ? (((qw0 + 15 - k0) >> 5) + 1) : 2;

        f32x4 st[4];
#pragma unroll
        for (int ip = 0; ip < 2; ip++)
          if (ip < npair) {
#pragma unroll
            for (int h2 = 0; h2 < 2; h2++) {
              const int kr = 32 * ip + 4 * h2 + kperm;
              const int swzk = (kr & 3) | ((kr & 8) >> 1);
              const char* kro = Kc + kr * 128;
              bf16x8 ka = *(const bf16x8*)(kro + ((g ^ swzk) << 4));
              bf16x8 kb = *(const bf16x8*)(kro + (((g | 4) ^ swzk) << 4));
              f32x4 z = {};
              z = MFMA_BF16(ka, qf0, z, 0, 0, 0);
              st[2 * ip + h2] = MFMA_BF16(kb, qf1, z, 0, 0, 0);
            }
          }

        float p[4][4];
        float mt = -INFINITY;
#pragma unroll
        for (int ip = 0; ip < 2; ip++)
          if (ip < npair) {
#pragma unroll
            for (int h2 = 0; h2 < 2; h2++)
#pragma unroll
              for (int r = 0; r < 4; r++) {
                const int kk = k0 + 32 * ip + 8 * g + 4 * h2 + r;
                float v = (float)st[2 * ip + h2][r] * 0.125f;
                if (lastT && kk > qi) v = -INFINITY;
                p[2 * ip + h2][r] = v;
                mt = fmaxf(mt, v);
              }
          }
        mt = fmaxf(mt, __shfl_xor(mt, 16, 64));
        mt = fmaxf(mt, __shfl_xor(mt, 32, 64));

        if (!__all(mt - m_i <= 8.0f)) {
          const float m_new = fmaxf(m_i, mt);
          const float alpha = __expf(m_i - m_new);
          l_i *= alpha;
#pragma unroll
          for (int dt = 0; dt < 4; dt++)
#pragma unroll
            for (int r = 0; r < 4; r++) ot[dt][r] *= alpha;
          m_i = m_new;
        }
        float s = 0.0f;
#pragma unroll
        for (int ip = 0; ip < 2; ip++)
          if (ip < npair) {
#pragma unroll
            for (int h2 = 0; h2 < 2; h2++)
#pragma unroll
              for (int r = 0; r < 4; r++) {
                float e = __expf(p[2 * ip + h2][r] - m_i);
                p[2 * ip + h2][r] = e;
                s += e;
              }
          }
        s += __shfl_xor(s, 16, 64);
        s += __shfl_xor(s, 32, 64);
        l_i += s;

#pragma unroll
        for (int ip = 0; ip < 2; ip++)
          if (ip < npair) {
            bf16x8 pf;
#pragma unroll
            for (int h2 = 0; h2 < 2; h2++)
#pragma unroll
              for (int r = 0; r < 4; r++) pf[4 * h2 + r] = (bf16)p[2 * ip + h2][r];
#pragma unroll
            for (int dt = 0; dt < 4; dt++) {
              const bf16x8 vf = *(const bf16x8*)(
                  Vc + (dt * 16 + l15) * 128 + (((4 * ip + g) ^ (l15 >> 1)) << 4));
              ot[dt] = MFMA_BF16(vf, pf, ot[dt], 0, 0, 0);
            }
          }
      }
      cur ^= 1;
    }

    const float inv = 1.0f / l_i;
    bf16* obase = O + (tokbase + qw0 + l15) * 1024 + hh * 64;
#pragma unroll
    for (int dt = 0; dt < 4; dt++) {
      bf16x4 ov;
#pragma unroll
      for (int r = 0; r < 4; r++) ov[r] = (bf16)(ot[dt][r] * inv);
      *(bf16x4*)(obase + dt * 16 + 4 * g) = ov;
    }
  }
}

// ---------------------------------------------------------------- launch
extern "C" void kernel_launch(void* const* d_in, const int* in_sizes, int n_in,
                              void* d_out, int out_size, void* d_ws, size_t ws_size,
                              hipStream_t stream) {
  const float* x = (const float*)d_in[0];
  const float* w_qkv = (const float*)d_in[1];
  const float* w_out = (const float*)d_in[2];
  const float* w_ff1 = (const float*)d_in[3];
  const float* w_ff2 = (const float*)d_in[4];
  float* out = (float*)d_out;

  char* ws = (char*)d_ws;
  size_t off = 0;
  auto alloc = [&](size_t bytes) {
    void* p = ws + off;
    off += (bytes + 255) & ~(size_t)255;
    return p;
  };
  const size_t M = 8192;
  bf16* X16   = (bf16*)alloc(M * 1024 * 2);
  bf16* WqkvT = (bf16*)alloc(3072ull * 1024 * 2);
  bf16* WoutT = (bf16*)alloc(1024ull * 1024 * 2);
  bf16* Wff1T = (bf16*)alloc(4096ull * 1024 * 2);
  bf16* Wff2T = (bf16*)alloc(1024ull * 4096 * 2);
  bf16* QKV   = (bf16*)alloc(M * 3072 * 2);
  bf16* Obuf  = (bf16*)alloc(M * 1024 * 2);
  float* x1   = (float*)alloc(M * 1024 * 4);
  bf16* x1b   = (bf16*)alloc(M * 1024 * 2);
  bf16* Hbuf  = (bf16*)alloc(M * 4096 * 2);

  cvt_f32_bf16<<<8192, 256, 0, stream>>>(x, X16, 8192 * 1024);
  transpose_w<<<dim3(3072 / 32, 1024 / 32), 256, 0, stream>>>(w_qkv, WqkvT, 1024, 3072);
  transpose_w<<<dim3(1024 / 32, 1024 / 32), 256, 0, stream>>>(w_out, WoutT, 1024, 1024);
  transpose_w<<<dim3(4096 / 32, 1024 / 32), 256, 0, stream>>>(w_ff1, Wff1T, 1024, 4096);
  transpose_w<<<dim3(1024 / 32, 4096 / 32), 256, 0, stream>>>(w_ff2, Wff2T, 4096, 1024);

  // grids: (M/256) * (N/(64*NF)); all multiples of 8 for XCD chunking
  gemm_bt<0, 4><<<32 * 12, 512, 0, stream>>>(X16, WqkvT, QKV, nullptr, nullptr, 1024, 3072);
  attn_fwd<<<dim3(64, 8), 512, 0, stream>>>(QKV, Obuf);
  gemm_bt<1, 2><<<32 * 8, 512, 0, stream>>>(Obuf, WoutT, x1b, x1, x, 1024, 1024);
  gemm_bt<2, 4><<<32 * 16, 512, 0, stream>>>(x1b, Wff1T, Hbuf, nullptr, nullptr, 1024, 4096);
  gemm_bt<3, 2><<<32 * 8, 512, 0, stream>>>(Hbuf, Wff2T, nullptr, out, x1, 4096, 1024);
}